// Round 5
// baseline (272.785 us; speedup 1.0000x reference)
//
#include <hip/hip_runtime.h>
#include <hip/hip_bf16.h>

#define N_NODES 100000
#define E_TOTAL 800000
#define E1      400000    // first min(4,k_max)*N edges -> scale-1 (subset of scale-2)
#define D       64
#define CAP     32        // max degree slots; P(deg>32 | Poisson(8)) ~ 1e-19

typedef short s16x8 __attribute__((ext_vector_type(8)));   // 8 bf16 bit patterns (4 VGPRs)
typedef float f32x4 __attribute__((ext_vector_type(4)));

// ws layout (u32 units):
//   flags[16] | cnt[N] | entries[N*CAP] | W1b[2048] | W2b[2048] | Wgb[4096]
//   | b1f[64] | b2f[64] | bgf[64] | Xb[N*32]   (Xb used only if ws_size permits)
#define WS_FLAGS   0
#define WS_CNT     16
#define WS_ENTRIES (WS_CNT + N_NODES)
#define WS_W1B     (WS_ENTRIES + N_NODES * CAP)   // byte offset 16-B aligned
#define WS_W2B     (WS_W1B + 2048)
#define WS_WGB     (WS_W2B + 2048)
#define WS_B1F     (WS_WGB + 4096)
#define WS_B2F     (WS_B1F + 64)
#define WS_BGF     (WS_B2F + 64)
#define WS_XB      (WS_BGF + 64)                  // byte offset 13233600, 16-B aligned
#define WS_NEED_BYTES ((size_t)(WS_XB + N_NODES * 32) * 4)   // ~26 MB

__device__ __forceinline__ float ldv(const void* p, size_t idx, int fp32)
{
    return fp32 ? ((const float*)p)[idx]
                : __bfloat162float(((const __hip_bfloat16*)p)[idx]);
}

// ---------------------------------------------------------------------------
// detect dtypes: flags[0]=edges are int64, flags[1]=x/W are fp32. One block.
// ---------------------------------------------------------------------------
__global__ __launch_bounds__(256) void detect_kernel(
    const int* __restrict__ ei, const unsigned short* __restrict__ xu,
    int* __restrict__ flags)
{
    __shared__ int s_e, s_f;
    const int tid = threadIdx.x;
    if (tid == 0) { s_e = 0; s_f = 0; }
    __syncthreads();
    if (tid < 16 && ei[2 * tid + 1] != 0) atomicOr(&s_e, 1);   // int32 ids in odd words
    { unsigned u = xu[tid]; if (((u >> 7) & 0xFF) >= 0x90) atomicOr(&s_f, 1); }
    __syncthreads();
    if (tid == 0) { flags[0] = (s_e == 0) ? 1 : 0; flags[1] = s_f; }
}

// ---------------------------------------------------------------------------
// parallel convert: x -> bf16 Xb (if enabled), weights -> bf16, biases -> f32.
// thread handles 8 elements; fully parallel (fixes R4's serial single-block prep).
// ---------------------------------------------------------------------------
__global__ __launch_bounds__(256) void convert_kernel(
    const void* __restrict__ xv,
    const void* __restrict__ W1v, const void* __restrict__ b1v,
    const void* __restrict__ W2v, const void* __restrict__ b2v,
    const void* __restrict__ Wgv, const void* __restrict__ bgv,
    unsigned* __restrict__ ws, int nx8)
{
    const int gid = blockIdx.x * 256 + threadIdx.x;
    const int fp32 = ((const int*)ws)[WS_FLAGS + 1];

    __hip_bfloat16* Xb  = (__hip_bfloat16*)(ws + WS_XB);
    __hip_bfloat16* W1b = (__hip_bfloat16*)(ws + WS_W1B);
    __hip_bfloat16* W2b = (__hip_bfloat16*)(ws + WS_W2B);
    __hip_bfloat16* Wgb = (__hip_bfloat16*)(ws + WS_WGB);

    if (gid < nx8) {                       // x: 8 elems/thread
        const size_t base = (size_t)gid * 8;
        if (fp32) {
            const float* xf = (const float*)xv;
#pragma unroll
            for (int j = 0; j < 8; ++j) Xb[base + j] = __float2bfloat16(xf[base + j]);
        } else {
            *(s16x8*)(Xb + base) = *((const s16x8*)xv + gid);   // plain 16-B copy
        }
    } else if (gid < nx8 + 2048) {         // weights: 16384 elems total
        const int j = gid - nx8;
        const int base = j * 8;
#pragma unroll
        for (int k = 0; k < 8; ++k) {
            const int i = base + k;
            if (i < 4096)       W1b[i]        = __float2bfloat16(ldv(W1v, i, fp32));
            else if (i < 8192)  W2b[i - 4096] = __float2bfloat16(ldv(W2v, i - 4096, fp32));
            else                Wgb[i - 8192] = __float2bfloat16(ldv(Wgv, i - 8192, fp32));
        }
    } else if (gid < nx8 + 2048 + 24) {    // biases: 192 elems
        const int j = gid - nx8 - 2048;
        float* b1f = (float*)(ws + WS_B1F);
#pragma unroll
        for (int k = 0; k < 8; ++k) {
            const int i = j * 8 + k;       // 0..191 over b1|b2|bg
            if (i < 64)       b1f[i] = ldv(b1v, i, fp32);
            else if (i < 128) b1f[i] = ldv(b2v, i - 64, fp32);   // contiguous b1f/b2f/bgf
            else              b1f[i] = ldv(bgv, i - 128, fp32);
        }
    }
}

// ---------------------------------------------------------------------------
// capped-slot CSR fill: cnt[src]++ -> entries[src*CAP+pos] = tgt | scale1bit
// ---------------------------------------------------------------------------
__global__ __launch_bounds__(256) void fill_kernel(const int* __restrict__ ei,
                                                   unsigned* __restrict__ ws)
{
    const int e = blockIdx.x * 256 + threadIdx.x;
    if (e >= E_TOTAL) return;
    const int f = ((const int*)ws)[WS_FLAGS];
    const int src = f ? ei[2 * e] : ei[e];
    const int tgt = f ? ei[2 * (E_TOTAL + e)] : ei[E_TOTAL + e];
    unsigned pos = atomicAdd(ws + WS_CNT + src, 1u);
    if (pos < CAP)
        ws[WS_ENTRIES + (size_t)src * CAP + pos] =
            (unsigned)tgt | ((e < E1) ? 0x80000000u : 0u);
}

// ---------------------------------------------------------------------------
// fused gather + MFMA epilogue. 4 waves/block, ONE WAVE OWNS 16 NODES
// end-to-end; no block-wide barriers (wave-private LDS region, same-wave
// RAW ordering handled by compiler lgkmcnt — verified pattern from R4).
//   phase A: mean-aggregate neighbor rows -> s1,s2 bf16 in LDS
//   phase B: O1 = S1 W1^T + b1, O2 = S2 W2^T + b2 (mfma_16x16x32_bf16)
//            G = sigmoid([O1 O2] Wg^T + bg); out = G*O1 + (1-G)*O2
// ---------------------------------------------------------------------------
__global__ __launch_bounds__(256) void fused_kernel(
    const unsigned* __restrict__ ws, const void* __restrict__ xv,
    void* __restrict__ outv, int use_xb)
{
    // [wave][row][136]: row stride 272 B (16-B aligned, odd-17 stride -> no conflicts)
    __shared__ __align__(16) __hip_bfloat16 sbuf[4][16][136];

    const int wave = threadIdx.x >> 6;
    const int lane = threadIdx.x & 63;
    const int m = lane & 15;          // A-row / C-col index
    const int q = lane >> 4;          // quad
    const int base = (blockIdx.x * 4 + wave) * 16;
    if (base >= N_NODES) return;      // wave-uniform early-out (tail block)

    const int fp32 = ((const int*)ws)[WS_FLAGS + 1];
    const __hip_bfloat16* Xb = (const __hip_bfloat16*)(ws + WS_XB);

    // ---- phase A: gather 16 nodes, write s1|s2 rows into wave's LDS ----
    for (int i = 0; i < 16; ++i) {
        const int n = base + i;
        const unsigned deg_raw = ws[WS_CNT + n];
        const int deg = (int)min(deg_raw, (unsigned)CAP);

        unsigned ent = (lane < deg) ? ws[WS_ENTRIES + (size_t)n * CAP + lane] : 0u;

        float sum1 = 0.0f, sum2 = 0.0f;
        int c1 = 0;
        for (int j = 0; j < deg; ++j) {
            const unsigned en = __builtin_amdgcn_readlane(ent, j);
            const int tgt = (int)(en & 0x7FFFFFFFu);
            const float val = use_xb
                ? __bfloat162float(Xb[(size_t)tgt * D + lane])
                : ldv(xv, (size_t)tgt * D + lane, fp32);
            sum2 += val;
            if (en & 0x80000000u) { sum1 += val; c1++; }
        }
        const float s1 = sum1 * (1.0f / ((float)c1 + 1e-6f));
        const float s2 = sum2 * (1.0f / ((float)deg_raw + 1e-6f));
        sbuf[wave][i][lane]      = __float2bfloat16(s1);
        sbuf[wave][i][64 + lane] = __float2bfloat16(s2);
    }

    // ---- phase B: MFMA epilogue over this wave's 16 nodes ----
    const s16x8* W1b = (const s16x8*)(ws + WS_W1B);
    const s16x8* W2b = (const s16x8*)(ws + WS_W2B);
    const s16x8* Wgb = (const s16x8*)(ws + WS_WGB);
    const float* b1f = (const float*)(ws + WS_B1F);
    const float* b2f = (const float*)(ws + WS_B2F);
    const float* bgf = (const float*)(ws + WS_BGF);

    // A-fragments: lane holds A[m][k=q*8+j] (all 16 s-rows consumed into regs
    // here, BEFORE the gate staging overwrites sbuf)
    const s16x8 a1c0 = *(const s16x8*)&sbuf[wave][m][q * 8];
    const s16x8 a1c1 = *(const s16x8*)&sbuf[wave][m][32 + q * 8];
    const s16x8 a2c0 = *(const s16x8*)&sbuf[wave][m][64 + q * 8];
    const s16x8 a2c1 = *(const s16x8*)&sbuf[wave][m][96 + q * 8];

    f32x4 acc1[4], acc2[4];
#pragma unroll
    for (int t = 0; t < 4; ++t) {
        const int n = t * 16 + m;      // output dim carried by lane (B n-index)
        f32x4 z = {0.f, 0.f, 0.f, 0.f};
        z = __builtin_amdgcn_mfma_f32_16x16x32_bf16(a1c0, W1b[n * 8 + q],     z, 0, 0, 0);
        z = __builtin_amdgcn_mfma_f32_16x16x32_bf16(a1c1, W1b[n * 8 + 4 + q], z, 0, 0, 0);
        f32x4 y = {0.f, 0.f, 0.f, 0.f};
        y = __builtin_amdgcn_mfma_f32_16x16x32_bf16(a2c0, W2b[n * 8 + q],     y, 0, 0, 0);
        y = __builtin_amdgcn_mfma_f32_16x16x32_bf16(a2c1, W2b[n * 8 + 4 + q], y, 0, 0, 0);
        const float bb1 = b1f[n], bb2 = b2f[n];
#pragma unroll
        for (int r = 0; r < 4; ++r) { z[r] += bb1; y[r] += bb2; }
        acc1[t] = z; acc2[t] = y;
    }

    // gate staging: C-layout (row=node_local=q*4+r, col=t*16+m) -> LDS [m][k]
#pragma unroll
    for (int t = 0; t < 4; ++t)
#pragma unroll
        for (int r = 0; r < 4; ++r) {
            sbuf[wave][q * 4 + r][t * 16 + m]      = __float2bfloat16(acc1[t][r]);
            sbuf[wave][q * 4 + r][64 + t * 16 + m] = __float2bfloat16(acc2[t][r]);
        }

    s16x8 ga[4];
#pragma unroll
    for (int c = 0; c < 4; ++c)
        ga[c] = *(const s16x8*)&sbuf[wave][m][c * 32 + q * 8];

#pragma unroll
    for (int t = 0; t < 4; ++t) {
        const int n = t * 16 + m;
        f32x4 g4 = {0.f, 0.f, 0.f, 0.f};
#pragma unroll
        for (int c = 0; c < 4; ++c)
            g4 = __builtin_amdgcn_mfma_f32_16x16x32_bf16(ga[c], Wgb[n * 16 + c * 4 + q], g4, 0, 0, 0);
        const float bb = bgf[n];
#pragma unroll
        for (int r = 0; r < 4; ++r) {
            const float g = 1.0f / (1.0f + __expf(-(g4[r] + bb)));
            const float v = g * acc1[t][r] + (1.0f - g) * acc2[t][r];
            const size_t node = (size_t)(base + q * 4 + r);
            if (fp32) ((float*)outv)[node * 64 + n] = v;
            else      ((__hip_bfloat16*)outv)[node * 64 + n] = __float2bfloat16(v);
        }
    }
}

// ---------------------------------------------------------------------------
extern "C" void kernel_launch(void* const* d_in, const int* in_sizes, int n_in,
                              void* d_out, int out_size, void* d_ws, size_t ws_size,
                              hipStream_t stream)
{
    const void* x  = d_in[0];
    const int*  ei = (const int*)d_in[1];
    unsigned* ws = (unsigned*)d_ws;

    // ws_size is constant across calls -> same work every call
    const int use_xb = (ws_size >= WS_NEED_BYTES) ? 1 : 0;
    const int nx8 = use_xb ? (N_NODES * D / 8) : 0;          // 800000 or 0
    const int nconv = nx8 + 2048 + 24;

    hipMemsetAsync(ws + WS_CNT, 0, N_NODES * sizeof(unsigned), stream);
    detect_kernel<<<1, 256, 0, stream>>>(ei, (const unsigned short*)x, (int*)ws);
    convert_kernel<<<(nconv + 255) / 256, 256, 0, stream>>>(
        x, d_in[2], d_in[3], d_in[4], d_in[5], d_in[6], d_in[7], ws, nx8);
    fill_kernel<<<(E_TOTAL + 255) / 256, 256, 0, stream>>>(ei, ws);
    fused_kernel<<<(N_NODES / 16 + 3) / 4, 256, 0, stream>>>(ws, x, d_out, use_xb);
}

// Round 7
// 234.100 us; speedup vs baseline: 1.1653x; 1.1653x over previous
//
#include <hip/hip_runtime.h>
#include <hip/hip_bf16.h>

#define N_NODES 100000
#define E_TOTAL 800000
#define E1      400000    // first min(4,k_max)*N edges -> scale-1 (subset of scale-2)
#define D       64
#define CAP     32        // max degree slots; P(deg>32 | Poisson(8)) ~ 2e-11/node

typedef short s16x8 __attribute__((ext_vector_type(8)));   // 8 bf16 bit patterns
typedef float f32x4 __attribute__((ext_vector_type(4)));

// ws layout (u32 units):
//   cnt[N] | entries[N*CAP] | W1b[2048] | W2b[2048] | Wgb[4096] | bias[192] | Xb[N*32]
#define WS_CNT     0
#define WS_ENTRIES (N_NODES)                        // byte 400000, 16-B aligned
#define WS_W1B     (WS_ENTRIES + N_NODES * CAP)     // byte 13200000, 16-B aligned
#define WS_W2B     (WS_W1B + 2048)
#define WS_WGB     (WS_W2B + 2048)
#define WS_BIAS    (WS_WGB + 4096)                  // b1[64] | b2[64] | bg[64] fp32
#define WS_XB      (WS_BIAS + 192)                  // byte 13233536, 16-B aligned
#define WS_NEED_BYTES ((size_t)(WS_XB + (size_t)N_NODES * D / 2) * 4)   // ~26 MB

// prep gid ranges  (R6 BUG FIX: x-convert must cover N*D = 6.4M elems, 8/thread)
#define R_X   (N_NODES * D / 8)      // 800000 threads: x convert, 8 elems/thread
#define R_W   (R_X + 2048)           // weights: 8 elems/thread (16384)
#define R_B   (R_W + 24)             // biases: 8 elems/thread (192)
#define R_F   (R_B + E_TOTAL)        // fill: 1 edge/thread
#define PREP_BLOCKS ((R_F + 255) / 256)

__device__ __forceinline__ float ldv(const void* p, size_t idx, int fp32)
{
    return fp32 ? ((const float*)p)[idx]
                : __bfloat162float(((const __hip_bfloat16*)p)[idx]);
}

// block-local dtype detection (blockDim.x == 256).
__device__ __forceinline__ void detect2(const int* ei, const unsigned short* xu,
                                        int* s2, int& e64, int& fp32)
{
    if (threadIdx.x == 0) { s2[0] = 0; s2[1] = 0; }
    __syncthreads();
    if (threadIdx.x < 16 && ei[2 * threadIdx.x + 1] != 0) atomicOr(&s2[0], 1);
    { unsigned u = xu[threadIdx.x]; if (((u >> 7) & 0xFF) >= 0x90) atomicOr(&s2[1], 1); }
    __syncthreads();
    e64 = (s2[0] == 0); fp32 = s2[1];
}

// ---------------------------------------------------------------------------
// prep: one launch does x->bf16 Xb, weights->bf16, biases->f32, CSR fill.
// cnt must be pre-zeroed (memsetAsync). Disjoint gid ranges, per-block detect.
// ---------------------------------------------------------------------------
__global__ __launch_bounds__(256) void prep_kernel(
    const void* __restrict__ xv, const int* __restrict__ ei,
    const void* __restrict__ W1v, const void* __restrict__ b1v,
    const void* __restrict__ W2v, const void* __restrict__ b2v,
    const void* __restrict__ Wgv, const void* __restrict__ bgv,
    unsigned* __restrict__ ws, int use_xb)
{
    __shared__ int s2[2];
    int e64, fp32;
    detect2(ei, (const unsigned short*)xv, s2, e64, fp32);

    const int gid = blockIdx.x * 256 + threadIdx.x;
    __hip_bfloat16* Xb  = (__hip_bfloat16*)(ws + WS_XB);
    __hip_bfloat16* W1b = (__hip_bfloat16*)(ws + WS_W1B);
    __hip_bfloat16* W2b = (__hip_bfloat16*)(ws + WS_W2B);
    __hip_bfloat16* Wgb = (__hip_bfloat16*)(ws + WS_WGB);
    float* bias = (float*)(ws + WS_BIAS);

    if (gid < R_X) {                          // x -> Xb: 8 elems/thread, all 6.4M
        if (use_xb && fp32) {
            const f32x4 v0 = ((const f32x4*)xv)[2 * gid];
            const f32x4 v1 = ((const f32x4*)xv)[2 * gid + 1];
            s16x8 o;
#pragma unroll
            for (int j = 0; j < 4; ++j) {
                o[j]     = (short)__bfloat16_as_ushort(__float2bfloat16(v0[j]));
                o[4 + j] = (short)__bfloat16_as_ushort(__float2bfloat16(v1[j]));
            }
            *(s16x8*)(Xb + (size_t)gid * 8) = o;   // 16-B aligned store
        }
    } else if (gid < R_W) {                   // weights: 16384 elems
        const int j = gid - R_X;
#pragma unroll
        for (int k = 0; k < 8; ++k) {
            const int i = j * 8 + k;
            if (i < 4096)       W1b[i]        = __float2bfloat16(ldv(W1v, i, fp32));
            else if (i < 8192)  W2b[i - 4096] = __float2bfloat16(ldv(W2v, i - 4096, fp32));
            else                Wgb[i - 8192] = __float2bfloat16(ldv(Wgv, i - 8192, fp32));
        }
    } else if (gid < R_B) {                   // biases: 192 elems
        const int j = gid - R_W;
#pragma unroll
        for (int k = 0; k < 8; ++k) {
            const int i = j * 8 + k;
            if (i < 64)       bias[i] = ldv(b1v, i, fp32);
            else if (i < 128) bias[i] = ldv(b2v, i - 64, fp32);
            else              bias[i] = ldv(bgv, i - 128, fp32);
        }
    } else if (gid < R_F) {                   // CSR fill
        const int e = gid - R_B;
        int src, tgt;
        if (e64) {
            const uint2 a = ((const uint2*)ei)[e];
            const uint2 b = ((const uint2*)ei)[E_TOTAL + e];
            src = (int)a.x; tgt = (int)b.x;
        } else {
            src = ei[e]; tgt = ei[E_TOTAL + e];
        }
        const unsigned pos = atomicAdd(ws + WS_CNT + src, 1u);
        if (pos < CAP)
            ws[WS_ENTRIES + (size_t)src * CAP + pos] =
                (unsigned)tgt | ((e < E1) ? 0x80000000u : 0u);
    }
}

// ---------------------------------------------------------------------------
// fused gather + MFMA epilogue. 256 thr = 4 waves = 16 nodes/block.
// Wave w gathers nodes base+4w..base+4w+3 (entry rows prefetched -> no serial
// latency chain), S -> LDS; barrier; all 4 waves split the epilogue by output
// dim slice (wave w = dims [16w,16w+16)); O staged in LDS; barrier; gate.
// Grid = N/16 = 6250 exactly (no tail, barriers convergent).
// ---------------------------------------------------------------------------
__global__ __launch_bounds__(256) void fused_kernel(
    const unsigned* __restrict__ ws, const void* __restrict__ xv,
    void* __restrict__ outv, int use_xb)
{
    __shared__ __align__(16) __hip_bfloat16 sS[16][136];  // s1|s2 rows per node
    __shared__ __align__(16) __hip_bfloat16 sO[16][136];  // o1|o2 rows per node
    __shared__ int s2d[2];

    // output dtype / gather source (per-block self-detect, no cross-kernel dep)
    if (threadIdx.x == 0) s2d[0] = 0;
    __syncthreads();
    { unsigned u = ((const unsigned short*)xv)[threadIdx.x];
      if (((u >> 7) & 0xFF) >= 0x90) atomicOr(&s2d[0], 1); }
    __syncthreads();
    const int fp32 = s2d[0];

    const int w    = threadIdx.x >> 6;
    const int lane = threadIdx.x & 63;
    const int base = blockIdx.x * 16;

    const __hip_bfloat16* xb = (use_xb && fp32)
        ? (const __hip_bfloat16*)(ws + WS_XB)
        : (const __hip_bfloat16*)xv;
    const float* xf = (const float*)xv;
    const int direct_f32 = (fp32 && !use_xb);

    // ---- phase A: gather. Prefetch all 4 entry rows, then accumulate. ----
    unsigned entv[4]; int degc[4]; unsigned degr[4];
#pragma unroll
    for (int i = 0; i < 4; ++i) {
        const int n = base + w * 4 + i;
        degr[i] = ws[WS_CNT + n];
        degc[i] = (int)min(degr[i], (unsigned)CAP);
        entv[i] = (lane < degc[i]) ? ws[WS_ENTRIES + (size_t)n * CAP + lane] : 0u;
    }
#pragma unroll
    for (int i = 0; i < 4; ++i) {
        const int dg = degc[i];
        float sum1 = 0.f, sum2 = 0.f;
        int c1 = 0;
        int j = 0;
        for (; j + 4 <= dg; j += 4) {
            const unsigned e0 = __builtin_amdgcn_readlane(entv[i], j);
            const unsigned e1 = __builtin_amdgcn_readlane(entv[i], j + 1);
            const unsigned e2 = __builtin_amdgcn_readlane(entv[i], j + 2);
            const unsigned e3 = __builtin_amdgcn_readlane(entv[i], j + 3);
            const size_t i0 = (size_t)(e0 & 0x7FFFFFFFu) * D + lane;
            const size_t i1 = (size_t)(e1 & 0x7FFFFFFFu) * D + lane;
            const size_t i2 = (size_t)(e2 & 0x7FFFFFFFu) * D + lane;
            const size_t i3 = (size_t)(e3 & 0x7FFFFFFFu) * D + lane;
            const float v0 = direct_f32 ? xf[i0] : __bfloat162float(xb[i0]);
            const float v1 = direct_f32 ? xf[i1] : __bfloat162float(xb[i1]);
            const float v2 = direct_f32 ? xf[i2] : __bfloat162float(xb[i2]);
            const float v3 = direct_f32 ? xf[i3] : __bfloat162float(xb[i3]);
            sum2 += (v0 + v1) + (v2 + v3);
            if (e0 & 0x80000000u) { sum1 += v0; c1++; }
            if (e1 & 0x80000000u) { sum1 += v1; c1++; }
            if (e2 & 0x80000000u) { sum1 += v2; c1++; }
            if (e3 & 0x80000000u) { sum1 += v3; c1++; }
        }
        for (; j < dg; ++j) {
            const unsigned en = __builtin_amdgcn_readlane(entv[i], j);
            const size_t ix = (size_t)(en & 0x7FFFFFFFu) * D + lane;
            const float v = direct_f32 ? xf[ix] : __bfloat162float(xb[ix]);
            sum2 += v;
            if (en & 0x80000000u) { sum1 += v; c1++; }
        }
        const int nl = w * 4 + i;
        sS[nl][lane]      = __float2bfloat16(sum1 * (1.0f / ((float)c1 + 1e-6f)));
        sS[nl][64 + lane] = __float2bfloat16(sum2 * (1.0f / ((float)degr[i] + 1e-6f)));
    }
    __syncthreads();

    // ---- phase B: MFMA epilogue; wave w computes output dims [16w,16w+16) ----
    const int m = lane & 15;          // A-row carrier / C-col index
    const int q = lane >> 4;          // quad
    const int nd = w * 16 + m;        // output dim this lane computes

    const s16x8* W1b = (const s16x8*)(ws + WS_W1B);
    const s16x8* W2b = (const s16x8*)(ws + WS_W2B);
    const s16x8* Wgb = (const s16x8*)(ws + WS_WGB);
    const float* bias = (const float*)(ws + WS_BIAS);

    // A-frags: lane holds A[m][k=q*8+j]
    const s16x8 a1c0 = *(const s16x8*)&sS[m][q * 8];
    const s16x8 a1c1 = *(const s16x8*)&sS[m][32 + q * 8];
    const s16x8 a2c0 = *(const s16x8*)&sS[m][64 + q * 8];
    const s16x8 a2c1 = *(const s16x8*)&sS[m][96 + q * 8];

    f32x4 z = {0.f, 0.f, 0.f, 0.f};
    z = __builtin_amdgcn_mfma_f32_16x16x32_bf16(a1c0, W1b[nd * 8 + q],     z, 0, 0, 0);
    z = __builtin_amdgcn_mfma_f32_16x16x32_bf16(a1c1, W1b[nd * 8 + 4 + q], z, 0, 0, 0);
    f32x4 y = {0.f, 0.f, 0.f, 0.f};
    y = __builtin_amdgcn_mfma_f32_16x16x32_bf16(a2c0, W2b[nd * 8 + q],     y, 0, 0, 0);
    y = __builtin_amdgcn_mfma_f32_16x16x32_bf16(a2c1, W2b[nd * 8 + 4 + q], y, 0, 0, 0);
    const float bb1 = bias[nd], bb2 = bias[64 + nd];
#pragma unroll
    for (int r = 0; r < 4; ++r) { z[r] += bb1; y[r] += bb2; }

    // stage O (C-layout: row=node_local=q*4+r, col=nd / 64+nd)
#pragma unroll
    for (int r = 0; r < 4; ++r) {
        sO[q * 4 + r][nd]      = __float2bfloat16(z[r]);
        sO[q * 4 + r][64 + nd] = __float2bfloat16(y[r]);
    }
    __syncthreads();

    // gate A-frags: A[m][k=c*32+q*8+j] over [O1|O2]
    s16x8 ga[4];
#pragma unroll
    for (int c = 0; c < 4; ++c)
        ga[c] = *(const s16x8*)&sO[m][c * 32 + q * 8];

    f32x4 g4 = {0.f, 0.f, 0.f, 0.f};
#pragma unroll
    for (int c = 0; c < 4; ++c)
        g4 = __builtin_amdgcn_mfma_f32_16x16x32_bf16(ga[c], Wgb[nd * 16 + c * 4 + q], g4, 0, 0, 0);
    const float bbg = bias[128 + nd];

#pragma unroll
    for (int r = 0; r < 4; ++r) {
        const float g = 1.0f / (1.0f + __expf(-(g4[r] + bbg)));
        const float v = g * z[r] + (1.0f - g) * y[r];
        const size_t node = (size_t)(base + q * 4 + r);
        if (fp32) ((float*)outv)[node * 64 + nd] = v;
        else      ((__hip_bfloat16*)outv)[node * 64 + nd] = __float2bfloat16(v);
    }
}

// ---------------------------------------------------------------------------
extern "C" void kernel_launch(void* const* d_in, const int* in_sizes, int n_in,
                              void* d_out, int out_size, void* d_ws, size_t ws_size,
                              hipStream_t stream)
{
    const void* x  = d_in[0];
    const int*  ei = (const int*)d_in[1];
    unsigned* ws = (unsigned*)d_ws;

    const int use_xb = (ws_size >= WS_NEED_BYTES) ? 1 : 0;   // constant per dataset

    hipMemsetAsync(ws + WS_CNT, 0, N_NODES * sizeof(unsigned), stream);
    prep_kernel<<<PREP_BLOCKS, 256, 0, stream>>>(
        x, ei, d_in[2], d_in[3], d_in[4], d_in[5], d_in[6], d_in[7], ws, use_xb);
    fused_kernel<<<N_NODES / 16, 256, 0, stream>>>(ws, x, d_out, use_xb);
}

// Round 8
// 211.374 us; speedup vs baseline: 1.2905x; 1.1075x over previous
//
#include <hip/hip_runtime.h>
#include <hip/hip_bf16.h>

#define N_NODES 100000
#define E_TOTAL 800000
#define E1      400000    // first min(4,k_max)*N edges -> scale-1 (subset of scale-2)
#define D       64
#define CAP     32        // max degree slots; P(deg>32 | Poisson(8)) ~ 2e-11/node

typedef short s16x8 __attribute__((ext_vector_type(8)));   // 8 bf16 bit patterns
typedef float f32x4 __attribute__((ext_vector_type(4)));

// ws layout (u32 units):
//   cnt[N] | entries[N*CAP] | W1b[2048] | W2b[2048] | Wgb[4096] | bias[192] | Xb[N*32]
#define WS_CNT     0
#define WS_ENTRIES (N_NODES)                        // byte 400000, 16-B aligned
#define WS_W1B     (WS_ENTRIES + N_NODES * CAP)     // byte 13200000, 16-B aligned
#define WS_W2B     (WS_W1B + 2048)
#define WS_WGB     (WS_W2B + 2048)
#define WS_BIAS    (WS_WGB + 4096)                  // b1[64] | b2[64] | bg[64] fp32
#define WS_XB      (WS_BIAS + 192)                  // byte 13233536, 16-B aligned
#define WS_NEED_BYTES ((size_t)(WS_XB + (size_t)N_NODES * D / 2) * 4)   // ~26 MB

// prep gid ranges
#define R_X   (N_NODES * D / 8)      // 800000 threads: x convert, 8 elems/thread
#define R_W   (R_X + 2048)           // weights: 8 elems/thread (16384)
#define R_B   (R_W + 24)             // biases: 8 elems/thread (192)
#define R_F   (R_B + E_TOTAL)        // fill: 1 edge/thread
#define PREP_BLOCKS ((R_F + 255) / 256)

__device__ __forceinline__ float ldv(const void* p, size_t idx, int fp32)
{
    return fp32 ? ((const float*)p)[idx]
                : __bfloat162float(((const __hip_bfloat16*)p)[idx]);
}

// block-local dtype detection (blockDim.x == 256).
__device__ __forceinline__ void detect2(const int* ei, const unsigned short* xu,
                                        int* s2, int& e64, int& fp32)
{
    if (threadIdx.x == 0) { s2[0] = 0; s2[1] = 0; }
    __syncthreads();
    if (threadIdx.x < 16 && ei[2 * threadIdx.x + 1] != 0) atomicOr(&s2[0], 1);
    { unsigned u = xu[threadIdx.x]; if (((u >> 7) & 0xFF) >= 0x90) atomicOr(&s2[1], 1); }
    __syncthreads();
    e64 = (s2[0] == 0); fp32 = s2[1];
}

// ---------------------------------------------------------------------------
// prep: one launch does x->bf16 Xb, weights->bf16, biases->f32, CSR fill.
// ---------------------------------------------------------------------------
__global__ __launch_bounds__(256) void prep_kernel(
    const void* __restrict__ xv, const int* __restrict__ ei,
    const void* __restrict__ W1v, const void* __restrict__ b1v,
    const void* __restrict__ W2v, const void* __restrict__ b2v,
    const void* __restrict__ Wgv, const void* __restrict__ bgv,
    unsigned* __restrict__ ws, int use_xb)
{
    __shared__ int s2[2];
    int e64, fp32;
    detect2(ei, (const unsigned short*)xv, s2, e64, fp32);

    const int gid = blockIdx.x * 256 + threadIdx.x;
    __hip_bfloat16* Xb  = (__hip_bfloat16*)(ws + WS_XB);
    __hip_bfloat16* W1b = (__hip_bfloat16*)(ws + WS_W1B);
    __hip_bfloat16* W2b = (__hip_bfloat16*)(ws + WS_W2B);
    __hip_bfloat16* Wgb = (__hip_bfloat16*)(ws + WS_WGB);
    float* bias = (float*)(ws + WS_BIAS);

    if (gid < R_X) {                          // x -> Xb: 8 elems/thread, all 6.4M
        if (use_xb && fp32) {
            const f32x4 v0 = ((const f32x4*)xv)[2 * gid];
            const f32x4 v1 = ((const f32x4*)xv)[2 * gid + 1];
            s16x8 o;
#pragma unroll
            for (int j = 0; j < 4; ++j) {
                o[j]     = (short)__bfloat16_as_ushort(__float2bfloat16(v0[j]));
                o[4 + j] = (short)__bfloat16_as_ushort(__float2bfloat16(v1[j]));
            }
            *(s16x8*)(Xb + (size_t)gid * 8) = o;
        }
    } else if (gid < R_W) {                   // weights: 16384 elems
        const int j = gid - R_X;
#pragma unroll
        for (int k = 0; k < 8; ++k) {
            const int i = j * 8 + k;
            if (i < 4096)       W1b[i]        = __float2bfloat16(ldv(W1v, i, fp32));
            else if (i < 8192)  W2b[i - 4096] = __float2bfloat16(ldv(W2v, i - 4096, fp32));
            else                Wgb[i - 8192] = __float2bfloat16(ldv(Wgv, i - 8192, fp32));
        }
    } else if (gid < R_B) {                   // biases: 192 elems
        const int j = gid - R_W;
#pragma unroll
        for (int k = 0; k < 8; ++k) {
            const int i = j * 8 + k;
            if (i < 64)       bias[i] = ldv(b1v, i, fp32);
            else if (i < 128) bias[i] = ldv(b2v, i - 64, fp32);
            else              bias[i] = ldv(bgv, i - 128, fp32);
        }
    } else if (gid < R_F) {                   // CSR fill
        const int e = gid - R_B;
        int src, tgt;
        if (e64) {
            const uint2 a = ((const uint2*)ei)[e];
            const uint2 b = ((const uint2*)ei)[E_TOTAL + e];
            src = (int)a.x; tgt = (int)b.x;
        } else {
            src = ei[e]; tgt = ei[E_TOTAL + e];
        }
        const unsigned pos = atomicAdd(ws + WS_CNT + src, 1u);
        if (pos < CAP)
            ws[WS_ENTRIES + (size_t)src * CAP + pos] =
                (unsigned)tgt | ((e < E1) ? 0x80000000u : 0u);
    }
}

// ---------------------------------------------------------------------------
// fused gather + MFMA epilogue. 256 thr = 4 waves = 16 nodes/block.
// R8 gather: one global_load_dword covers TWO full x-rows (lane L -> row
// L>>5, dim pair 2*(L&31)); ~deg/2 independent predicated loads per node;
// bf16 unpack via shifts; scale-1 count via ballot; one shfl_xor(32)
// reduction round. Epilogue (MFMA) unchanged from R7.
// ---------------------------------------------------------------------------
__global__ __launch_bounds__(256) void fused_kernel(
    const unsigned* __restrict__ ws, const void* __restrict__ xv,
    void* __restrict__ outv, int use_xb)
{
    __shared__ __align__(16) __hip_bfloat16 sS[16][136];  // s1|s2 rows per node
    __shared__ __align__(16) __hip_bfloat16 sO[16][136];  // o1|o2 rows per node
    __shared__ int s2d[2];

    // output dtype / gather source (per-block self-detect)
    if (threadIdx.x == 0) s2d[0] = 0;
    __syncthreads();
    { unsigned u = ((const unsigned short*)xv)[threadIdx.x];
      if (((u >> 7) & 0xFF) >= 0x90) atomicOr(&s2d[0], 1); }
    __syncthreads();
    const int fp32 = s2d[0];

    const int w    = threadIdx.x >> 6;
    const int lane = threadIdx.x & 63;
    const int base = blockIdx.x * 16;

    const int direct_f32 = (fp32 && !use_xb);     // fallback: no Xb space
    const char* xb = (use_xb && fp32) ? (const char*)(ws + WS_XB) : (const char*)xv;
    const float* xf = (const float*)xv;

    // ---- phase A: prefetch entry rows + degree for this wave's 4 nodes ----
    unsigned entv[4]; int degc[4]; unsigned degr[4];
#pragma unroll
    for (int i = 0; i < 4; ++i) {
        const int n = base + w * 4 + i;
        degr[i] = ws[WS_CNT + n];
        degc[i] = (int)min(degr[i], (unsigned)CAP);
        entv[i] = (lane < degc[i]) ? ws[WS_ENTRIES + (size_t)n * CAP + lane] : 0u;
    }

    const int half = lane >> 5;       // which of the 2 rows in a chunk
    const int cc   = lane & 31;       // dim-pair index: dims 2cc, 2cc+1

#pragma unroll
    for (int i = 0; i < 4; ++i) {
        const int nl = w * 4 + i;
        // scale-1 edge count: one ballot (lanes >= degc hold entv=0)
        const int c1 = (int)__popcll(__ballot(entv[i] & 0x80000000u));

        float s1x = 0.f, s1y = 0.f, s2x = 0.f, s2y = 0.f;

        if (!direct_f32) {
            const int chunks = (degc[i] + 1) >> 1;
#pragma unroll 4
            for (int r = 0; r < chunks; ++r) {
                const int j = 2 * r + half;
                const unsigned en = __shfl(entv[i], j);       // ds_bpermute
                if (j < degc[i]) {
                    const size_t tgt = (size_t)(en & 0x7FFFFFFFu);
                    const unsigned u = *(const unsigned*)(xb + (tgt << 7) + (cc << 2));
                    const float fx = __uint_as_float(u << 16);          // dim 2cc
                    const float fy = __uint_as_float(u & 0xFFFF0000u);  // dim 2cc+1
                    const float fl = (en & 0x80000000u) ? 1.f : 0.f;
                    s2x += fx; s2y += fy;
                    s1x = fmaf(fl, fx, s1x); s1y = fmaf(fl, fy, s1y);
                }
            }
        } else {
            // fallback: direct fp32 x, scalar per-edge row loads (rare path)
            for (int j = 0; j < degc[i]; ++j) {
                const unsigned en = __builtin_amdgcn_readlane(entv[i], j);
                const float v = xf[(size_t)(en & 0x7FFFFFFFu) * D + lane];
                s2x += v;
                if (en & 0x80000000u) s1x += v;
            }
        }

        if (!direct_f32) {
            // reduce the two row-halves: partner lane = lane ^ 32
            s1x += __shfl_xor(s1x, 32); s1y += __shfl_xor(s1y, 32);
            s2x += __shfl_xor(s2x, 32); s2y += __shfl_xor(s2y, 32);

            const float inv1 = 1.0f / ((float)c1 + 1e-6f);
            const float inv2 = 1.0f / ((float)degr[i] + 1e-6f);
            if (lane < 32) {   // lanes 0..31 own dim pairs 0..31
                const __hip_bfloat162 p1 = __float22bfloat162_rn({s1x * inv1, s1y * inv1});
                const __hip_bfloat162 p2 = __float22bfloat162_rn({s2x * inv2, s2y * inv2});
                *(__hip_bfloat162*)&sS[nl][2 * cc]      = p1;
                *(__hip_bfloat162*)&sS[nl][64 + 2 * cc] = p2;
            }
        } else {
            const float inv1 = 1.0f / ((float)c1 + 1e-6f);
            const float inv2 = 1.0f / ((float)degr[i] + 1e-6f);
            sS[nl][lane]      = __float2bfloat16(s1x * inv1);
            sS[nl][64 + lane] = __float2bfloat16(s2x * inv2);
        }
    }
    __syncthreads();

    // ---- phase B: MFMA epilogue; wave w computes output dims [16w,16w+16) ----
    const int m = lane & 15;          // A-row carrier / C-col index
    const int q = lane >> 4;          // quad
    const int nd = w * 16 + m;        // output dim this lane computes

    const s16x8* W1b = (const s16x8*)(ws + WS_W1B);
    const s16x8* W2b = (const s16x8*)(ws + WS_W2B);
    const s16x8* Wgb = (const s16x8*)(ws + WS_WGB);
    const float* bias = (const float*)(ws + WS_BIAS);

    const s16x8 a1c0 = *(const s16x8*)&sS[m][q * 8];
    const s16x8 a1c1 = *(const s16x8*)&sS[m][32 + q * 8];
    const s16x8 a2c0 = *(const s16x8*)&sS[m][64 + q * 8];
    const s16x8 a2c1 = *(const s16x8*)&sS[m][96 + q * 8];

    f32x4 z = {0.f, 0.f, 0.f, 0.f};
    z = __builtin_amdgcn_mfma_f32_16x16x32_bf16(a1c0, W1b[nd * 8 + q],     z, 0, 0, 0);
    z = __builtin_amdgcn_mfma_f32_16x16x32_bf16(a1c1, W1b[nd * 8 + 4 + q], z, 0, 0, 0);
    f32x4 y = {0.f, 0.f, 0.f, 0.f};
    y = __builtin_amdgcn_mfma_f32_16x16x32_bf16(a2c0, W2b[nd * 8 + q],     y, 0, 0, 0);
    y = __builtin_amdgcn_mfma_f32_16x16x32_bf16(a2c1, W2b[nd * 8 + 4 + q], y, 0, 0, 0);
    const float bb1 = bias[nd], bb2 = bias[64 + nd];
#pragma unroll
    for (int r = 0; r < 4; ++r) { z[r] += bb1; y[r] += bb2; }

#pragma unroll
    for (int r = 0; r < 4; ++r) {
        sO[q * 4 + r][nd]      = __float2bfloat16(z[r]);
        sO[q * 4 + r][64 + nd] = __float2bfloat16(y[r]);
    }
    __syncthreads();

    s16x8 ga[4];
#pragma unroll
    for (int c = 0; c < 4; ++c)
        ga[c] = *(const s16x8*)&sO[m][c * 32 + q * 8];

    f32x4 g4 = {0.f, 0.f, 0.f, 0.f};
#pragma unroll
    for (int c = 0; c < 4; ++c)
        g4 = __builtin_amdgcn_mfma_f32_16x16x32_bf16(ga[c], Wgb[nd * 16 + c * 4 + q], g4, 0, 0, 0);
    const float bbg = bias[128 + nd];

#pragma unroll
    for (int r = 0; r < 4; ++r) {
        const float g = 1.0f / (1.0f + __expf(-(g4[r] + bbg)));
        const float v = g * z[r] + (1.0f - g) * y[r];
        const size_t node = (size_t)(base + q * 4 + r);
        if (fp32) ((float*)outv)[node * 64 + nd] = v;
        else      ((__hip_bfloat16*)outv)[node * 64 + nd] = __float2bfloat16(v);
    }
}

// ---------------------------------------------------------------------------
extern "C" void kernel_launch(void* const* d_in, const int* in_sizes, int n_in,
                              void* d_out, int out_size, void* d_ws, size_t ws_size,
                              hipStream_t stream)
{
    const void* x  = d_in[0];
    const int*  ei = (const int*)d_in[1];
    unsigned* ws = (unsigned*)d_ws;

    const int use_xb = (ws_size >= WS_NEED_BYTES) ? 1 : 0;   // constant per dataset

    hipMemsetAsync(ws + WS_CNT, 0, N_NODES * sizeof(unsigned), stream);
    prep_kernel<<<PREP_BLOCKS, 256, 0, stream>>>(
        x, ei, d_in[2], d_in[3], d_in[4], d_in[5], d_in[6], d_in[7], ws, use_xb);
    fused_kernel<<<N_NODES / 16, 256, 0, stream>>>(ws, x, d_out, use_xb);
}